// Round 5
// baseline (657.670 us; speedup 1.0000x reference)
//
#include <hip/hip_runtime.h>
#include <hip/hip_bf16.h>
#include <math.h>

// ---------------------------------------------------------------------------
// Real spherical harmonics, l_max = 8, Wikipedia convention, (l,m) lexicographic
// index = l*l + l + m. Output (N, 81) float32, row-major.
//
// R5: register-staged burst copy (discriminator between two worlds).
//   - 5 structurally different kernels all give dur 648-656us; decomposition
//     dur = harness-fill(413us) + ~240us holds every round.
//   - World A: kernel ~238us, store-ack-serialized: unroll-4 copy recycles
//     ~16 VGPRs -> compiler inserts s_waitcnt vmcnt(K) INSIDE the copy loop
//     -> ~5 serialized ack-latencies per tile, only ~8 stores/wave in flight.
//   - Fix: stage the whole 20.25-float4 copy in 21 DISTINCT f32x4 registers
//     (full unroll, static idx), then 21 back-to-back nt stores. No vmcnt
//     wait until next tile's copy, by which time ~1.7k cy of compute has
//     hidden the ack latency. In-flight stores/CU: ~50KB -> ~145KB.
//   - Predict: World A -> dur ~525-555. World B (kernel invisible, harness
//     floor) -> unchanged, declare ROOFLINE next round.
// ---------------------------------------------------------------------------

#define LMAX 8
#define NSH  81        // (LMAX+1)^2
#define BPT  64        // points per tile == block size (one wave)
#define PERSIST_BLOCKS (7 * 256)   // 7 blocks/CU (LDS-capped) x 256 CUs
#define NF4  (BPT * NSH / 4)       // 1296 float4 per tile
#define F4PT (NF4 / BPT)           // 20 full float4 per thread
#define REM  (NF4 - F4PT * BPT)    // 16 leftover float4 (threads 0..15)

typedef float f32x4 __attribute__((ext_vector_type(4)));   // nt-store-compatible

// ---- compile-time k(l,m) table (includes sqrt(2) for m>0) ------------------
constexpr double c_sqrt(double x) {
    double g = (x > 1.0) ? x : 1.0;
    for (int i = 0; i < 80; ++i) g = 0.5 * (g + x / g);
    return g;
}
constexpr double c_fact(int n) {
    double r = 1.0;
    for (int i = 2; i <= n; ++i) r *= (double)i;
    return r;
}
struct KTab {
    float k[LMAX + 1][LMAX + 1];   // k[l][m], m<=l
    constexpr KTab() : k{} {
        for (int l = 0; l <= LMAX; ++l)
            for (int m = 0; m <= l; ++m) {
                double v = c_sqrt((2.0 * l + 1.0) / (4.0 * 3.14159265358979323846)
                                  * c_fact(l - m) / c_fact(l + m));
                if (m > 0) v *= 1.41421356237309504880;   // sqrt(2)
                k[l][m] = (float)v;
            }
    }
};
constexpr KTab KT{};

// zero-instruction ordering fence: blocks compiler reordering of LDS ops
// across it; HW executes same-wave DS ops in order, so no waitcnt needed.
__device__ __forceinline__ void wave_fence() {
    asm volatile("" ::: "memory");
    __builtin_amdgcn_wave_barrier();
}

__device__ __forceinline__ void compute_row(float x, float y, float z, float* row) {
    const float r2xy = x * x + y * y;
    const float r    = sqrtf(r2xy + z * z);
    const float rxy  = sqrtf(r2xy);
    const float ct   = z / r;
    const float st   = rxy / r;
    const float irxy = (rxy > 0.0f) ? (1.0f / rxy) : 0.0f;
    const float cp   = x * irxy;
    const float sp   = y * irxy;

    // cos(m phi), sin(m phi)
    float cm[LMAX + 1], sm[LMAX + 1];
    cm[0] = 1.0f; sm[0] = 0.0f;
#pragma unroll
    for (int m = 1; m <= LMAX; ++m) {
        cm[m] = cm[m - 1] * cp - sm[m - 1] * sp;
        sm[m] = sm[m - 1] * cp + cm[m - 1] * sp;
    }

    // associated Legendre (no Condon-Shortley), P[l][m], fully static indexing
    float P[LMAX + 1][LMAX + 1];
    P[0][0] = 1.0f;
#pragma unroll
    for (int m = 1; m <= LMAX; ++m)
        P[m][m] = (float)(2 * m - 1) * st * P[m - 1][m - 1];
#pragma unroll
    for (int m = 0; m < LMAX; ++m)
        P[m + 1][m] = (float)(2 * m + 1) * ct * P[m][m];
#pragma unroll
    for (int m = 0; m <= LMAX; ++m) {
#pragma unroll
        for (int l = m + 2; l <= LMAX; ++l) {
            P[l][m] = ((float)(2 * l - 1) * ct * P[l - 1][m]
                       - (float)(l + m - 1) * P[l - 2][m]) * (1.0f / (float)(l - m));
        }
    }

    // emit into LDS row: bank = (17*t + j) % 32 -> 2-way across 64 lanes (free)
#pragma unroll
    for (int l = 0; l <= LMAX; ++l) {
        const int base = l * l + l;
        row[base] = KT.k[l][0] * P[l][0];
#pragma unroll
        for (int m = 1; m <= l; ++m) {
            const float kp = KT.k[l][m] * P[l][m];
            row[base + m] = kp * cm[m];
            row[base - m] = kp * sm[m];
        }
    }
}

__global__ __launch_bounds__(BPT)
void sh_kernel(const float* __restrict__ xyz, float* __restrict__ out, int n) {
    __shared__ float lds[BPT * NSH];   // 20736 B -> 7 blocks/CU

    const int t      = threadIdx.x;
    const int ntiles = (n + BPT - 1) / BPT;

    int tile = blockIdx.x;
    if (tile >= ntiles) return;

    // ---- prefetch first tile's xyz ----
    float x = 0.0f, y = 0.0f, z = 1.0f;   // safe dummies for p >= n lanes
    {
        const int p = tile * BPT + t;
        if (p < n) {
            x = xyz[3 * p + 0];
            y = xyz[3 * p + 1];
            z = xyz[3 * p + 2];
        }
    }

    for (;;) {
        const int next_tile = tile + gridDim.x;

        // ---- issue next tile's loads NOW (older than this tile's stores in
        //      vmcnt order -> waiting for them never drains the stores) ----
        float nx = 0.0f, ny = 0.0f, nz = 1.0f;
        if (next_tile < ntiles) {
            const int np = next_tile * BPT + t;
            if (np < n) {
                nx = xyz[3 * np + 0];
                ny = xyz[3 * np + 1];
                nz = xyz[3 * np + 2];
            }
        }

        // ---- compute current tile into LDS (hides prefetch latency AND
        //      the previous tile's store-ack latency) ----
        compute_row(x, y, z, &lds[t * NSH]);
        wave_fence();   // order: ds_writes above before ds_reads below (HW in-order)

        // ---- register-staged burst copy-out ----
        const int p0    = tile * BPT;
        const int valid = (n - p0 < BPT) ? (n - p0) : BPT;
        float* op = out + (size_t)p0 * NSH;
        if (valid == BPT) {
            f32x4* o4 = (f32x4*)op;
            const f32x4* l4 = (const f32x4*)lds;
            // stage: 20 (+1 for t<16) DISTINCT registers, static indices only
            f32x4 buf[F4PT];
#pragma unroll
            for (int i = 0; i < F4PT; ++i)
                buf[i] = l4[t + i * BPT];
            f32x4 bufr = {0.f, 0.f, 0.f, 0.f};
            if (t < REM) bufr = l4[F4PT * BPT + t];
            // burst: back-to-back nt stores, no intra-copy vmcnt waits
#pragma unroll
            for (int i = 0; i < F4PT; ++i)
                __builtin_nontemporal_store(buf[i], &o4[t + i * BPT]);
            if (t < REM)
                __builtin_nontemporal_store(bufr, &o4[F4PT * BPT + t]);
        } else {
            const int nf = valid * NSH;
            for (int i = t; i < nf; i += BPT) {
                float v = lds[i];
                __builtin_nontemporal_store(v, &op[i]);
            }
        }

        if (next_tile >= ntiles) break;
        wave_fence();   // order: ds_reads above before next tile's ds_writes
        tile = next_tile;
        x = nx; y = ny; z = nz;
    }
}

extern "C" void kernel_launch(void* const* d_in, const int* in_sizes, int n_in,
                              void* d_out, int out_size, void* d_ws, size_t ws_size,
                              hipStream_t stream) {
    const float* xyz = (const float*)d_in[0];
    float*       out = (float*)d_out;
    const int n = in_sizes[0] / 3;
    const int ntiles = (n + BPT - 1) / BPT;
    const int grid = (ntiles < PERSIST_BLOCKS) ? ntiles : PERSIST_BLOCKS;
    if (grid > 0) {
        hipLaunchKernelGGL(sh_kernel, dim3(grid), dim3(BPT), 0, stream, xyz, out, n);
    }
}

// Round 6
// 629.323 us; speedup vs baseline: 1.0450x; 1.0450x over previous
//
#include <hip/hip_runtime.h>
#include <hip/hip_bf16.h>
#include <math.h>

// ---------------------------------------------------------------------------
// Real spherical harmonics, l_max = 8. Output (N, 81) float32, row-major.
//
// R6: producer/consumer wave specialization (fill-kernel mimic).
//   - Six schedule variants all give dur 648-658; kernel residual ~237us is
//     invariant to every intra-wave change (barriers, nt, burst, prefetch).
//   - Last untested axis: wave ROLE structure. Wave 0 computes tiles into a
//     double-buffered LDS; wave 1 does nothing but ds_read_b128 + back-to-back
//     nt global_store_dwordx4 -- structurally identical to fillBufferAligned,
//     which hits 6.28 TB/s at ~3 waves/CU. No s_barrier in the loop => no
//     vmcnt drain ever touches the store wave.
//   - Handshake: LDS epoch flags (ready[2]/done[2]) + s_sleep polling.
//     Producer: poll done[b]==u -> compute -> lgkmcnt(0) -> ready[b]=u+1.
//     Consumer: poll ready[b]==u+1 -> read+store -> lgkmcnt(0) -> done[b]=u+1.
//     Same-wave DS ops complete in order (basis of R2's verified fence-only
//     reuse); lgkmcnt(0) before each flag-set gives cross-wave data-before-
//     flag ordering. One __syncthreads after flag init only.
//   - 3 WGs/CU (41.5KB LDS) = 3 store + 3 compute waves/CU. Compute supply
//     ~42us/CU, store issue ~9us/CU, HBM floor 107us => BW-bound if no wall.
//   - Decisive: World A -> dur ~520-545. Unchanged -> residual is harness
//     fixed work; declare ROOFLINE next round.
// ---------------------------------------------------------------------------

#define LMAX 8
#define NSH  81                    // (LMAX+1)^2
#define PTS  64                    // points per tile
#define TPB  128                   // 2 waves per workgroup
#define NWG  (3 * 256)             // 3 WGs/CU (LDS-capped) x 256 CUs
#define NF4  (PTS * NSH / 4)       // 1296 float4 per tile
#define F4PT (NF4 / 64)            // 20 full float4 per lane
#define REM  (NF4 - F4PT * 64)     // 16 leftover float4 (lanes 0..15)

typedef float f32x4 __attribute__((ext_vector_type(4)));

// ---- compile-time k(l,m) table (includes sqrt(2) for m>0) ------------------
constexpr double c_sqrt(double x) {
    double g = (x > 1.0) ? x : 1.0;
    for (int i = 0; i < 80; ++i) g = 0.5 * (g + x / g);
    return g;
}
constexpr double c_fact(int n) {
    double r = 1.0;
    for (int i = 2; i <= n; ++i) r *= (double)i;
    return r;
}
struct KTab {
    float k[LMAX + 1][LMAX + 1];   // k[l][m], m<=l
    constexpr KTab() : k{} {
        for (int l = 0; l <= LMAX; ++l)
            for (int m = 0; m <= l; ++m) {
                double v = c_sqrt((2.0 * l + 1.0) / (4.0 * 3.14159265358979323846)
                                  * c_fact(l - m) / c_fact(l + m));
                if (m > 0) v *= 1.41421356237309504880;   // sqrt(2)
                k[l][m] = (float)v;
            }
    }
};
constexpr KTab KT{};

__device__ __forceinline__ void compiler_fence() {
    asm volatile("" ::: "memory");
}
__device__ __forceinline__ void lds_drain() {
    asm volatile("s_waitcnt lgkmcnt(0)" ::: "memory");
}

__device__ __forceinline__ void compute_row(float x, float y, float z, float* row) {
    const float r2xy = x * x + y * y;
    const float r    = sqrtf(r2xy + z * z);
    const float rxy  = sqrtf(r2xy);
    const float ct   = z / r;
    const float st   = rxy / r;
    const float irxy = (rxy > 0.0f) ? (1.0f / rxy) : 0.0f;
    const float cp   = x * irxy;
    const float sp   = y * irxy;

    float cm[LMAX + 1], sm[LMAX + 1];
    cm[0] = 1.0f; sm[0] = 0.0f;
#pragma unroll
    for (int m = 1; m <= LMAX; ++m) {
        cm[m] = cm[m - 1] * cp - sm[m - 1] * sp;
        sm[m] = sm[m - 1] * cp + cm[m - 1] * sp;
    }

    float P[LMAX + 1][LMAX + 1];
    P[0][0] = 1.0f;
#pragma unroll
    for (int m = 1; m <= LMAX; ++m)
        P[m][m] = (float)(2 * m - 1) * st * P[m - 1][m - 1];
#pragma unroll
    for (int m = 0; m < LMAX; ++m)
        P[m + 1][m] = (float)(2 * m + 1) * ct * P[m][m];
#pragma unroll
    for (int m = 0; m <= LMAX; ++m) {
#pragma unroll
        for (int l = m + 2; l <= LMAX; ++l) {
            P[l][m] = ((float)(2 * l - 1) * ct * P[l - 1][m]
                       - (float)(l + m - 1) * P[l - 2][m]) * (1.0f / (float)(l - m));
        }
    }

    // row stride 81 floats: bank = (17*t + j) % 32 -> 2-way across 64 lanes (free)
#pragma unroll
    for (int l = 0; l <= LMAX; ++l) {
        const int base = l * l + l;
        row[base] = KT.k[l][0] * P[l][0];
#pragma unroll
        for (int m = 1; m <= l; ++m) {
            const float kp = KT.k[l][m] * P[l][m];
            row[base + m] = kp * cm[m];
            row[base - m] = kp * sm[m];
        }
    }
}

__global__ __launch_bounds__(TPB)
void sh_kernel(const float* __restrict__ xyz, float* __restrict__ out, int n) {
    __shared__ float data[2][PTS * NSH];   // 2 x 20736 B
    __shared__ int   flags[4];             // [0],[1]=ready(b) ; [2],[3]=done(b)

    const int t    = threadIdx.x & 63;
    const int wave = threadIdx.x >> 6;
    const int ntiles = (n + PTS - 1) / PTS;   // grid <= ntiles guaranteed

    if (threadIdx.x == 0) {
        flags[0] = 0; flags[1] = 0; flags[2] = 0; flags[3] = 0;
    }
    __syncthreads();   // one-time; makes flag init visible to both waves

    if (wave == 0) {
        // ------------------------- producer wave ---------------------------
        int tile = blockIdx.x;
        int j = 0;
        float x = 0.0f, y = 0.0f, z = 1.0f;
        {
            const int p = tile * PTS + t;
            if (p < n) { x = xyz[3*p]; y = xyz[3*p+1]; z = xyz[3*p+2]; }
        }
        for (;;) {
            const int next_tile = tile + gridDim.x;
            // prefetch next tile's xyz under this tile's compute
            float nx = 0.0f, ny = 0.0f, nz = 1.0f;
            if (next_tile < ntiles) {
                const int np = next_tile * PTS + t;
                if (np < n) { nx = xyz[3*np]; ny = xyz[3*np+1]; nz = xyz[3*np+2]; }
            }
            const int b = j & 1;
            const int u = j >> 1;
            // wait until consumer released buffer b (usage u complete count == u)
            {
                volatile int* dn = &flags[2 + b];
                while (*dn != u) __builtin_amdgcn_s_sleep(2);
            }
            compiler_fence();
            compute_row(x, y, z, &data[b][t * NSH]);
            lds_drain();                       // data writes complete before flag
            if (t == 0) flags[b] = u + 1;      // publish ready
            ++j;
            if (next_tile >= ntiles) break;
            tile = next_tile;
            x = nx; y = ny; z = nz;
        }
    } else {
        // ------------------------- consumer (store) wave --------------------
        int tile = blockIdx.x;
        int j = 0;
        for (;;) {
            const int b = j & 1;
            const int u = j >> 1;
            {
                volatile int* rd = &flags[b];
                while (*rd != u + 1) __builtin_amdgcn_s_sleep(2);
            }
            compiler_fence();
            const int p0    = tile * PTS;
            const int valid = (n - p0 < PTS) ? (n - p0) : PTS;
            float* op = out + (size_t)p0 * NSH;
            if (valid == PTS) {
                f32x4* o4 = (f32x4*)op;
                const f32x4* l4 = (const f32x4*)data[b];
                // pipeline: all ds_reads into distinct regs, then pure store burst
                f32x4 buf[F4PT];
#pragma unroll
                for (int i = 0; i < F4PT; ++i)
                    buf[i] = l4[t + i * 64];
                f32x4 bufr = {0.f, 0.f, 0.f, 0.f};
                if (t < REM) bufr = l4[F4PT * 64 + t];
#pragma unroll
                for (int i = 0; i < F4PT; ++i)
                    __builtin_nontemporal_store(buf[i], &o4[t + i * 64]);
                if (t < REM)
                    __builtin_nontemporal_store(bufr, &o4[F4PT * 64 + t]);
            } else {
                const int nf = valid * NSH;
                for (int i = t; i < nf; i += 64) {
                    float v = data[b][i];
                    __builtin_nontemporal_store(v, &op[i]);
                }
            }
            lds_drain();                       // ds_reads complete before release
            if (t == 0) flags[2 + b] = u + 1;  // release buffer
            ++j;
            const int next_tile = tile + gridDim.x;
            if (next_tile >= ntiles) break;
            tile = next_tile;
        }
    }
}

extern "C" void kernel_launch(void* const* d_in, const int* in_sizes, int n_in,
                              void* d_out, int out_size, void* d_ws, size_t ws_size,
                              hipStream_t stream) {
    const float* xyz = (const float*)d_in[0];
    float*       out = (float*)d_out;
    const int n = in_sizes[0] / 3;
    const int ntiles = (n + PTS - 1) / PTS;
    const int grid = (ntiles < NWG) ? ntiles : NWG;   // grid <= ntiles: no idle WGs
    if (grid > 0) {
        hipLaunchKernelGGL(sh_kernel, dim3(grid), dim3(TPB), 0, stream, xyz, out, n);
    }
}